// Round 1
// baseline (1076.259 us; speedup 1.0000x reference)
//
#include <hip/hip_runtime.h>
#include <cstdint>
#include <cstddef>

constexpr int NN  = 100000;
constexpr int EE  = 1600000;
constexpr int HID = 128;
constexpr int NCLS = 40;
constexpr int NB  = (NN + 1023) / 1024;   // 98 scan chunks of 1024

// ---------------------------------------------------------------- degree + norm
__global__ __launch_bounds__(256) void deg_k(const int* __restrict__ src, const int* __restrict__ dst,
                                             int* __restrict__ ocnt, int* __restrict__ icnt) {
    int e = blockIdx.x * 256 + threadIdx.x;
    if (e < EE) {
        atomicAdd(&ocnt[src[e]], 1);
        atomicAdd(&icnt[dst[e]], 1);
    }
}

__global__ __launch_bounds__(256) void norm_k(const int* __restrict__ ocnt, const int* __restrict__ icnt,
                                              float* __restrict__ onorm, float* __restrict__ inorm) {
    int i = blockIdx.x * 256 + threadIdx.x;
    if (i < NN) {
        int oc = ocnt[i]; if (oc < 1) oc = 1;
        int ic = icnt[i]; if (ic < 1) ic = 1;
        onorm[i] = rsqrtf((float)oc);
        inorm[i] = rsqrtf((float)ic);
    }
}

// ---------------------------------------------------------------- CSR build (counting sort by dst)
// chunk = 1024 elems, per-thread 4 consecutive
__global__ __launch_bounds__(256) void scan_sum_k(const int* __restrict__ icnt, int* __restrict__ bsum) {
    __shared__ int sc[256];
    int b = blockIdx.x, t = threadIdx.x;
    int base = b * 1024 + t * 4;
    int s = 0;
#pragma unroll
    for (int j = 0; j < 4; j++) { int idx = base + j; s += (idx < NN) ? icnt[idx] : 0; }
    sc[t] = s; __syncthreads();
    for (int off = 128; off > 0; off >>= 1) {
        if (t < off) sc[t] += sc[t + off];
        __syncthreads();
    }
    if (t == 0) bsum[b] = sc[0];
}

__global__ void scan_top_k(const int* __restrict__ bsum, int* __restrict__ boff, int* __restrict__ rowptr) {
    if (threadIdx.x == 0 && blockIdx.x == 0) {
        int run = 0;
        for (int i = 0; i < NB; i++) { boff[i] = run; run += bsum[i]; }
        rowptr[NN] = run;   // == EE
    }
}

__global__ __launch_bounds__(256) void scan_chunk_k(const int* __restrict__ icnt, const int* __restrict__ boff,
                                                    int* __restrict__ rowptr) {
    __shared__ int sc[256];
    int b = blockIdx.x, t = threadIdx.x;
    int base = b * 1024 + t * 4;
    int c[4];
#pragma unroll
    for (int j = 0; j < 4; j++) { int idx = base + j; c[j] = (idx < NN) ? icnt[idx] : 0; }
    int s = c[0] + c[1] + c[2] + c[3];
    sc[t] = s; __syncthreads();
    for (int off = 1; off < 256; off <<= 1) {
        int v = (t >= off) ? sc[t - off] : 0;
        __syncthreads();
        sc[t] += v;
        __syncthreads();
    }
    int excl = sc[t] - s + boff[b];
#pragma unroll
    for (int j = 0; j < 4; j++) {
        int idx = base + j;
        if (idx < NN) rowptr[idx] = excl;
        excl += c[j];
    }
}

__global__ __launch_bounds__(256) void scatter_k(const int* __restrict__ src, const int* __restrict__ dst,
                                                 const int* __restrict__ rowptr, int* __restrict__ fill,
                                                 int* __restrict__ col) {
    int e = blockIdx.x * 256 + threadIdx.x;
    if (e < EE) {
        int d = dst[e];
        int pos = atomicAdd(&fill[d], 1);
        col[rowptr[d] + pos] = src[e];
    }
}

// ---------------------------------------------------------------- aggregation: one wave per dst node
// out[n][:] = sum_{s in in-nbrs(n)} out_norm[s] * h[s][:]
__global__ __launch_bounds__(256) void agg_k(const float* __restrict__ h, const int* __restrict__ rowptr,
                                             const int* __restrict__ col, const float* __restrict__ onorm,
                                             float* __restrict__ out) {
    int w = (int)((blockIdx.x * 256 + threadIdx.x) >> 6);   // wave id == node id (uniform per wave)
    if (w >= NN) return;
    int lane = threadIdx.x & 63;
    int beg = rowptr[w], end = rowptr[w + 1];
    const float2* h2 = (const float2*)h;
    float2 acc; acc.x = 0.f; acc.y = 0.f;
    int i = beg;
    for (; i + 1 < end; i += 2) {
        int s0 = col[i], s1 = col[i + 1];
        float n0 = onorm[s0], n1 = onorm[s1];
        float2 v0 = h2[(size_t)s0 * 64 + lane];
        float2 v1 = h2[(size_t)s1 * 64 + lane];
        acc.x += n0 * v0.x + n1 * v1.x;
        acc.y += n0 * v0.y + n1 * v1.y;
    }
    if (i < end) {
        int s = col[i];
        float n = onorm[s];
        float2 v = h2[(size_t)s * 64 + lane];
        acc.x += n * v.x;
        acc.y += n * v.y;
    }
    ((float2*)out)[(size_t)w * 64 + lane] = acc;
}

// ---------------------------------------------------------------- fp32 GEMM: out = act((rowscale .* in) @ W + b)
// in: [nrows][128] row-major; W: [128][CS] row-major; out: [nrows][CS]
// block = 64 rows x CP cols, 256 threads, K in two 64-phases, TM=4 x TN per thread
template <int CP, int TN, int CS, bool RELU, bool HAS_SCALE>
__global__ __launch_bounds__(256) void gemm_k(const float* __restrict__ in, const float* __restrict__ rowscale,
                                              const float* __restrict__ W, const float* __restrict__ bias,
                                              float* __restrict__ out, int nrows) {
    constexpr int BR = 64, KT = 64, TM = 4;
    static_assert(CP / TN == 16, "need 16 col groups");
    __shared__ float As[BR * (KT + 1)];     // row-major, +1 pad -> 2-way bank alias (free)
    __shared__ float Ws[KT * CP];
    const int tid  = threadIdx.x;
    const int row0 = blockIdx.x * BR;
    const int rg   = tid & 15;              // 16 row groups * 4 rows
    const int cg   = tid >> 4;              // 16 col groups * TN cols
    float acc[TM][TN];
#pragma unroll
    for (int i = 0; i < TM; i++)
#pragma unroll
        for (int j = 0; j < TN; j++) acc[i][j] = 0.f;

    for (int kt = 0; kt < 128; kt += KT) {
        __syncthreads();
        // stage W[kt..kt+63][0..CP)
        if (CP == 128) {
            const float4* W4 = (const float4*)(W + (size_t)kt * CP);
            float4* Wd = (float4*)Ws;
#pragma unroll
            for (int j = 0; j < 8; j++) Wd[j * 256 + tid] = W4[j * 256 + tid];
        } else {  // classifier: real cols = CS (=40), zero-pad to CP (=64)
            for (int idx = tid; idx < KT * CP; idx += 256) {
                int k = idx >> 6, c = idx & 63;
                Ws[idx] = (c < CS) ? W[(size_t)(kt + k) * CS + c] : 0.f;
            }
        }
        // stage A tile (64 rows x 64 k), optional row scaling
#pragma unroll
        for (int j = 0; j < 4; j++) {
            int flat = j * 256 + tid;       // 1024 float4 slots
            int r    = flat >> 4;
            int k4   = (flat & 15) << 2;
            int grow = row0 + r;
            float4 v; v.x = 0.f; v.y = 0.f; v.z = 0.f; v.w = 0.f;
            if (grow < nrows) {
                v = *(const float4*)(in + (size_t)grow * 128 + kt + k4);
                if (HAS_SCALE) { float s = rowscale[grow]; v.x *= s; v.y *= s; v.z *= s; v.w *= s; }
            }
            float* ap = &As[r * (KT + 1) + k4];
            ap[0] = v.x; ap[1] = v.y; ap[2] = v.z; ap[3] = v.w;
        }
        __syncthreads();
#pragma unroll 8
        for (int k = 0; k < KT; k++) {
            float a[TM];
#pragma unroll
            for (int i = 0; i < TM; i++) a[i] = As[(rg * TM + i) * (KT + 1) + k];
            float b[TN];
#pragma unroll
            for (int j = 0; j < TN; j += 4) {
                float4 bv = *(const float4*)&Ws[k * CP + cg * TN + j];
                b[j] = bv.x; b[j + 1] = bv.y; b[j + 2] = bv.z; b[j + 3] = bv.w;
            }
#pragma unroll
            for (int i = 0; i < TM; i++)
#pragma unroll
                for (int j = 0; j < TN; j++) acc[i][j] = fmaf(a[i], b[j], acc[i][j]);
        }
    }
    // epilogue (no barriers below -> early return safe)
    int cb = cg * TN;
    if (cb >= CS) return;
    float bv[TN];
#pragma unroll
    for (int j = 0; j < TN; j++) bv[j] = bias[cb + j];
#pragma unroll
    for (int i = 0; i < TM; i++) {
        int grow = row0 + rg * TM + i;
        if (grow < nrows) {
#pragma unroll
            for (int j = 0; j < TN; j += 4) {
                float4 o;
                o.x = acc[i][j + 0] + bv[j + 0];
                o.y = acc[i][j + 1] + bv[j + 1];
                o.z = acc[i][j + 2] + bv[j + 2];
                o.w = acc[i][j + 3] + bv[j + 3];
                if (RELU) {
                    o.x = fmaxf(o.x, 0.f); o.y = fmaxf(o.y, 0.f);
                    o.z = fmaxf(o.z, 0.f); o.w = fmaxf(o.w, 0.f);
                }
                *(float4*)(out + (size_t)grow * CS + cb + j) = o;
            }
        }
    }
}

// ---------------------------------------------------------------- launch
extern "C" void kernel_launch(void* const* d_in, const int* in_sizes, int n_in,
                              void* d_out, int out_size, void* d_ws, size_t ws_size,
                              hipStream_t stream) {
    const float* x   = (const float*)d_in[0];
    const int*   src = (const int*)d_in[1];
    const int*   dst = (const int*)d_in[2];
    const float* W1  = (const float*)d_in[3];
    const float* b1  = (const float*)d_in[4];
    const float* W2  = (const float*)d_in[5];
    const float* b2  = (const float*)d_in[6];
    const float* Wg  = (const float*)d_in[7];   // [3][128][128]
    const float* bg  = (const float*)d_in[8];   // [3][128]
    const float* Wc  = (const float*)d_in[9];   // [128][40]
    const float* bc  = (const float*)d_in[10];  // [40]
    float* out = (float*)d_out;

    char* ws = (char*)d_ws;
    size_t off = 0;
    auto alloc = [&](size_t bytes) -> void* {
        void* p = ws + off;
        off += (bytes + 255) & ~(size_t)255;
        return p;
    };
    float* h0     = (float*)alloc((size_t)NN * HID * 4);
    float* h1     = (float*)alloc((size_t)NN * HID * 4);
    float* onorm  = (float*)alloc((size_t)NN * 4);
    float* inorm  = (float*)alloc((size_t)NN * 4);
    int*   ocnt   = (int*)alloc((size_t)NN * 4);
    int*   icnt   = (int*)alloc((size_t)NN * 4);
    int*   fill   = (int*)alloc((size_t)NN * 4);
    int*   rowptr = (int*)alloc((size_t)(NN + 1) * 4);
    int*   col    = (int*)alloc((size_t)EE * 4);
    int*   bsum   = (int*)alloc((size_t)NB * 4);
    int*   boff   = (int*)alloc((size_t)NB * 4);

    hipMemsetAsync(ocnt, 0, (size_t)NN * 4, stream);
    hipMemsetAsync(icnt, 0, (size_t)NN * 4, stream);
    hipMemsetAsync(fill, 0, (size_t)NN * 4, stream);

    deg_k<<<(EE + 255) / 256, 256, 0, stream>>>(src, dst, ocnt, icnt);
    norm_k<<<(NN + 255) / 256, 256, 0, stream>>>(ocnt, icnt, onorm, inorm);
    scan_sum_k<<<NB, 256, 0, stream>>>(icnt, bsum);
    scan_top_k<<<1, 64, 0, stream>>>(bsum, boff, rowptr);
    scan_chunk_k<<<NB, 256, 0, stream>>>(icnt, boff, rowptr);
    scatter_k<<<(EE + 255) / 256, 256, 0, stream>>>(src, dst, rowptr, fill, col);

    const int gemm_grid = (NN + 63) / 64;   // 1563
    // h0 = x @ W1 + b1
    gemm_k<128, 8, 128, false, false><<<gemm_grid, 256, 0, stream>>>(x, nullptr, W1, b1, h0, NN);
    // h1 = h0 @ W2 + b2
    gemm_k<128, 8, 128, false, false><<<gemm_grid, 256, 0, stream>>>(h0, nullptr, W2, b2, h1, NN);
    // 3x GraphConv + ReLU
    for (int l = 0; l < 3; l++) {
        agg_k<<<(NN * 64 + 255) / 256, 256, 0, stream>>>(h1, rowptr, col, onorm, h0);
        gemm_k<128, 8, 128, true, true><<<gemm_grid, 256, 0, stream>>>(
            h0, inorm, Wg + (size_t)l * 128 * 128, bg + (size_t)l * 128, h1, NN);
    }
    // classifier: out = h1 @ Wc + bc
    gemm_k<64, 4, 40, false, false><<<gemm_grid, 256, 0, stream>>>(h1, nullptr, Wc, bc, out, NN);
}

// Round 2
// 916.149 us; speedup vs baseline: 1.1748x; 1.1748x over previous
//
#include <hip/hip_runtime.h>
#include <cstdint>
#include <cstddef>

constexpr int NN  = 100000;
constexpr int EE  = 1600000;
constexpr int HID = 128;
constexpr int NB  = (NN + 1023) / 1024;   // 98 scan chunks of 1024

typedef float f32x4_t __attribute__((ext_vector_type(4)));
typedef short bf16x8_t __attribute__((ext_vector_type(8)));

static __device__ __forceinline__ short f2bf(float f) {
    union { float f; unsigned u; } x; x.f = f;
    unsigned r = x.u + 0x7FFF + ((x.u >> 16) & 1);   // RN-even
    return (short)(r >> 16);
}
static __device__ __forceinline__ float bf2f(short b) {
    union { unsigned u; float f; } x; x.u = ((unsigned)(unsigned short)b) << 16;
    return x.f;
}

// ---------------------------------------------------------------- degree + norm
__global__ __launch_bounds__(256) void deg_k(const int* __restrict__ src, const int* __restrict__ dst,
                                             int* __restrict__ ocnt, int* __restrict__ icnt) {
    int e = blockIdx.x * 256 + threadIdx.x;
    if (e < EE) {
        atomicAdd(&ocnt[src[e]], 1);
        atomicAdd(&icnt[dst[e]], 1);
    }
}

__global__ __launch_bounds__(256) void norm_k(const int* __restrict__ ocnt, const int* __restrict__ icnt,
                                              float* __restrict__ onorm, float* __restrict__ inorm) {
    int i = blockIdx.x * 256 + threadIdx.x;
    if (i < NN) {
        int oc = ocnt[i]; if (oc < 1) oc = 1;
        int ic = icnt[i]; if (ic < 1) ic = 1;
        onorm[i] = rsqrtf((float)oc);
        inorm[i] = rsqrtf((float)ic);
    }
}

// ---------------------------------------------------------------- CSR build (counting sort by dst)
__global__ __launch_bounds__(256) void scan_sum_k(const int* __restrict__ icnt, int* __restrict__ bsum) {
    __shared__ int sc[256];
    int b = blockIdx.x, t = threadIdx.x;
    int base = b * 1024 + t * 4;
    int s = 0;
#pragma unroll
    for (int j = 0; j < 4; j++) { int idx = base + j; s += (idx < NN) ? icnt[idx] : 0; }
    sc[t] = s; __syncthreads();
    for (int off = 128; off > 0; off >>= 1) {
        if (t < off) sc[t] += sc[t + off];
        __syncthreads();
    }
    if (t == 0) bsum[b] = sc[0];
}

__global__ void scan_top_k(const int* __restrict__ bsum, int* __restrict__ boff, int* __restrict__ rowptr) {
    if (threadIdx.x == 0 && blockIdx.x == 0) {
        int run = 0;
        for (int i = 0; i < NB; i++) { boff[i] = run; run += bsum[i]; }
        rowptr[NN] = run;   // == EE
    }
}

__global__ __launch_bounds__(256) void scan_chunk_k(const int* __restrict__ icnt, const int* __restrict__ boff,
                                                    int* __restrict__ rowptr) {
    __shared__ int sc[256];
    int b = blockIdx.x, t = threadIdx.x;
    int base = b * 1024 + t * 4;
    int c[4];
#pragma unroll
    for (int j = 0; j < 4; j++) { int idx = base + j; c[j] = (idx < NN) ? icnt[idx] : 0; }
    int s = c[0] + c[1] + c[2] + c[3];
    sc[t] = s; __syncthreads();
    for (int off = 1; off < 256; off <<= 1) {
        int v = (t >= off) ? sc[t - off] : 0;
        __syncthreads();
        sc[t] += v;
        __syncthreads();
    }
    int excl = sc[t] - s + boff[b];
#pragma unroll
    for (int j = 0; j < 4; j++) {
        int idx = base + j;
        if (idx < NN) rowptr[idx] = excl;
        excl += c[j];
    }
}

__global__ __launch_bounds__(256) void scatter_k(const int* __restrict__ src, const int* __restrict__ dst,
                                                 const int* __restrict__ rowptr, int* __restrict__ fill,
                                                 int* __restrict__ col) {
    int e = blockIdx.x * 256 + threadIdx.x;
    if (e < EE) {
        int d = dst[e];
        int pos = atomicAdd(&fill[d], 1);
        col[rowptr[d] + pos] = src[e];
    }
}

// ---------------------------------------------------------------- aggregation
// one wave per dst node; half-wave (32 lanes x float4) per edge, 2 edges in
// flight per half (4 per wave). h is PRE-SCALED by out_norm (fused in GEMM
// epilogue), so the inner loop is pure gather+add.
__global__ __launch_bounds__(256) void agg_k(const float4* __restrict__ h4, const int* __restrict__ rowptr,
                                             const int* __restrict__ col, float4* __restrict__ out) {
    int w = (int)((blockIdx.x * 256 + threadIdx.x) >> 6);
    if (w >= NN) return;
    int lane = threadIdx.x & 63;
    int half = lane >> 5;
    int l32  = lane & 31;
    int beg = rowptr[w], end = rowptr[w + 1];
    float ax = 0.f, ay = 0.f, az = 0.f, aw = 0.f;
    int i = beg + half;
    for (; i + 2 < end; i += 4) {          // per half: edges i, i+2
        int s0 = col[i], s1 = col[i + 2];
        float4 v0 = h4[(size_t)s0 * 32 + l32];
        float4 v1 = h4[(size_t)s1 * 32 + l32];
        ax += v0.x + v1.x; ay += v0.y + v1.y;
        az += v0.z + v1.z; aw += v0.w + v1.w;
    }
    if (i < end) {
        int s = col[i];
        float4 v = h4[(size_t)s * 32 + l32];
        ax += v.x; ay += v.y; az += v.z; aw += v.w;
    }
    ax += __shfl_xor(ax, 32); ay += __shfl_xor(ay, 32);
    az += __shfl_xor(az, 32); aw += __shfl_xor(aw, 32);
    if (half == 0) {
        float4 o; o.x = ax; o.y = ay; o.z = az; o.w = aw;
        out[(size_t)w * 32 + l32] = o;
    }
}

// ---------------------------------------------------------------- split-bf16 MFMA GEMM
// out[r][c] = act( (inscale[r] * in[r][:]) @ W + bias ) * outscale[r]
// in: [nrows][128] fp32. W: [128][ncols] fp32 (ncols = NT*16 or 40 for NT=3).
// A = Ah + Al (bf16 split), W = Wh + Wl staged once per block into LDS in
// B-fragment order; C ~= Ah@Wh + Al@Wh + Ah@Wl via mfma_f32_16x16x32_bf16.
// Fragment layouts (verified m89/m91): A[m=lane&15][k=(lane>>4)*8+j],
// B[k=(lane>>4)*8+j][n=lane&15], C col=lane&15 row=(lane>>4)*4+reg.
// block = 256 thr = 4 waves, 16 rows/wave -> 64 rows per group; persistent grid.
template <int NT, bool RELU, bool INSCALE, bool OUTSCALE>
__global__ __launch_bounds__(256) void mfma_gemm_k(
    const float* __restrict__ in, const float* __restrict__ inscale,
    const float* __restrict__ W, const float* __restrict__ bias,
    float* __restrict__ out, const float* __restrict__ outscale,
    int nrows, int ncols, int ngroups) {

    __shared__ short Bh[NT * 2048];   // [nt][kblk(4)][lane(64)][j(8)]
    __shared__ short Bl[NT * 2048];

    const int t = threadIdx.x;

    // ---- stage W (fp32 -> bf16 hi/lo fragments), once per block
    if constexpr (NT == 8) {
        for (int j = 0; j < 16; j++) {
            int fi = (j * 256 + t) * 4;              // 4 consecutive floats, same k
            int k = fi >> 7, n0 = fi & 127;
            float4 wv = *(const float4*)(W + fi);
            float wa[4] = {wv.x, wv.y, wv.z, wv.w};
#pragma unroll
            for (int c = 0; c < 4; c++) {
                int n = n0 + c;
                int nt = n >> 4, kblk = k >> 5, ksub = k & 31;
                int lane_ = ((ksub >> 3) << 4) | (n & 15);
                int sidx = ((nt * 4 + kblk) * 64 + lane_) * 8 + (ksub & 7);
                short hi = f2bf(wa[c]);
                short lo = f2bf(wa[c] - bf2f(hi));
                Bh[sidx] = hi; Bl[sidx] = lo;
            }
        }
    } else {  // classifier: 40 real cols, pad to NT*16=48
        for (int idx = t; idx < 128 * 64; idx += 256) {
            int k = idx >> 6, n = idx & 63;
            if (n < NT * 16) {
                float w = (n < 40) ? W[k * 40 + n] : 0.f;
                int nt = n >> 4, kblk = k >> 5, ksub = k & 31;
                int lane_ = ((ksub >> 3) << 4) | (n & 15);
                int sidx = ((nt * 4 + kblk) * 64 + lane_) * 8 + (ksub & 7);
                short hi = f2bf(w);
                short lo = f2bf(w - bf2f(hi));
                Bh[sidx] = hi; Bl[sidx] = lo;
            }
        }
    }
    __syncthreads();   // LDS read-only below; no more barriers

    const int wave = t >> 6;
    const int lane = t & 63;
    const int m    = lane & 15;
    const int kq   = lane >> 4;

    for (int g = blockIdx.x; g < ngroups; g += gridDim.x) {
        int grow0 = g * 64 + wave * 16;
        int row   = grow0 + m;
        bool rv   = row < nrows;

        // load + split-convert A fragments for all 4 k-blocks
        bf16x8_t Ah[4], Al[4];
        float s = 1.f;
        if (INSCALE && rv) s = inscale[row];
#pragma unroll
        for (int kb = 0; kb < 4; kb++) {
            const float* ap = in + (size_t)row * 128 + kb * 32 + kq * 8;
            float4 p0, p1;
            if (rv) { p0 = *(const float4*)ap; p1 = *(const float4*)(ap + 4); }
            else    { p0 = make_float4(0,0,0,0); p1 = make_float4(0,0,0,0); }
            float av[8] = {p0.x, p0.y, p0.z, p0.w, p1.x, p1.y, p1.z, p1.w};
#pragma unroll
            for (int j = 0; j < 8; j++) {
                float v = INSCALE ? av[j] * s : av[j];
                short hi = f2bf(v);
                Ah[kb][j] = hi;
                Al[kb][j] = f2bf(v - bf2f(hi));
            }
        }

        // per-row output scale (C rows for this lane: grow0 + kq*4 + r)
        int crow0 = grow0 + kq * 4;
        float osr[4];
#pragma unroll
        for (int r = 0; r < 4; r++) {
            int crow = crow0 + r;
            osr[r] = (OUTSCALE && crow < nrows) ? outscale[crow] : 1.f;
        }

#pragma unroll
        for (int nt = 0; nt < NT; nt++) {
            f32x4_t acc = {0.f, 0.f, 0.f, 0.f};
#pragma unroll
            for (int kb = 0; kb < 4; kb++) {
                const bf16x8_t bh = *(const bf16x8_t*)&Bh[((nt * 4 + kb) * 64 + lane) * 8];
                const bf16x8_t bl = *(const bf16x8_t*)&Bl[((nt * 4 + kb) * 64 + lane) * 8];
                acc = __builtin_amdgcn_mfma_f32_16x16x32_bf16(Ah[kb], bh, acc, 0, 0, 0);
                acc = __builtin_amdgcn_mfma_f32_16x16x32_bf16(Al[kb], bh, acc, 0, 0, 0);
                acc = __builtin_amdgcn_mfma_f32_16x16x32_bf16(Ah[kb], bl, acc, 0, 0, 0);
            }
            // epilogue: C col = nt*16 + m, rows crow0 + r
            int ccol = nt * 16 + m;
            bool cv = (NT == 8) ? true : (ccol < ncols);
            float bv = cv ? bias[ccol] : 0.f;
#pragma unroll
            for (int r = 0; r < 4; r++) {
                int crow = crow0 + r;
                if (crow < nrows && cv) {
                    float v = acc[r] + bv;
                    if (RELU) v = fmaxf(v, 0.f);
                    v *= osr[r];
                    out[(size_t)crow * ncols + ccol] = v;
                }
            }
        }
    }
}

// ---------------------------------------------------------------- launch
extern "C" void kernel_launch(void* const* d_in, const int* in_sizes, int n_in,
                              void* d_out, int out_size, void* d_ws, size_t ws_size,
                              hipStream_t stream) {
    const float* x   = (const float*)d_in[0];
    const int*   src = (const int*)d_in[1];
    const int*   dst = (const int*)d_in[2];
    const float* W1  = (const float*)d_in[3];
    const float* b1  = (const float*)d_in[4];
    const float* W2  = (const float*)d_in[5];
    const float* b2  = (const float*)d_in[6];
    const float* Wg  = (const float*)d_in[7];   // [3][128][128]
    const float* bg  = (const float*)d_in[8];   // [3][128]
    const float* Wc  = (const float*)d_in[9];   // [128][40]
    const float* bc  = (const float*)d_in[10];  // [40]
    float* out = (float*)d_out;

    char* ws = (char*)d_ws;
    size_t off = 0;
    auto alloc = [&](size_t bytes) -> void* {
        void* p = ws + off;
        off += (bytes + 255) & ~(size_t)255;
        return p;
    };
    float* h0     = (float*)alloc((size_t)NN * HID * 4);
    float* h1     = (float*)alloc((size_t)NN * HID * 4);
    float* onorm  = (float*)alloc((size_t)NN * 4);
    float* inorm  = (float*)alloc((size_t)NN * 4);
    int*   ocnt   = (int*)alloc((size_t)NN * 4);
    int*   icnt   = (int*)alloc((size_t)NN * 4);
    int*   fill   = (int*)alloc((size_t)NN * 4);
    int*   rowptr = (int*)alloc((size_t)(NN + 1) * 4);
    int*   col    = (int*)alloc((size_t)EE * 4);
    int*   bsum   = (int*)alloc((size_t)NB * 4);
    int*   boff   = (int*)alloc((size_t)NB * 4);

    hipMemsetAsync(ocnt, 0, (size_t)NN * 4, stream);
    hipMemsetAsync(icnt, 0, (size_t)NN * 4, stream);
    hipMemsetAsync(fill, 0, (size_t)NN * 4, stream);

    deg_k<<<(EE + 255) / 256, 256, 0, stream>>>(src, dst, ocnt, icnt);
    norm_k<<<(NN + 255) / 256, 256, 0, stream>>>(ocnt, icnt, onorm, inorm);
    scan_sum_k<<<NB, 256, 0, stream>>>(icnt, bsum);
    scan_top_k<<<1, 64, 0, stream>>>(bsum, boff, rowptr);
    scan_chunk_k<<<NB, 256, 0, stream>>>(icnt, boff, rowptr);
    scatter_k<<<(EE + 255) / 256, 256, 0, stream>>>(src, dst, rowptr, fill, col);

    const int ngroups = (NN + 63) / 64;   // 1563
    const int ggrid   = 512;              // persistent: ~3 groups/block

    // h0 = x @ W1 + b1
    mfma_gemm_k<8, false, false, false><<<ggrid, 256, 0, stream>>>(
        x, nullptr, W1, b1, h0, nullptr, NN, 128, ngroups);
    // h1 = (h0 @ W2 + b2) * onorm   (pre-scaled for agg)
    mfma_gemm_k<8, false, false, true><<<ggrid, 256, 0, stream>>>(
        h0, nullptr, W2, b2, h1, onorm, NN, 128, ngroups);
    // 3x GraphConv + ReLU
    for (int l = 0; l < 3; l++) {
        agg_k<<<(NN * 64 + 255) / 256, 256, 0, stream>>>(
            (const float4*)h1, rowptr, col, (float4*)h0);
        if (l < 2) {
            mfma_gemm_k<8, true, true, true><<<ggrid, 256, 0, stream>>>(
                h0, inorm, Wg + (size_t)l * 128 * 128, bg + (size_t)l * 128, h1, onorm, NN, 128, ngroups);
        } else {
            mfma_gemm_k<8, true, true, false><<<ggrid, 256, 0, stream>>>(
                h0, inorm, Wg + (size_t)l * 128 * 128, bg + (size_t)l * 128, h1, nullptr, NN, 128, ngroups);
        }
    }
    // classifier: out = h1 @ Wc + bc
    mfma_gemm_k<3, false, false, false><<<ggrid, 256, 0, stream>>>(
        h1, nullptr, Wc, bc, out, nullptr, NN, 40, ngroups);
}

// Round 3
// 867.482 us; speedup vs baseline: 1.2407x; 1.0561x over previous
//
#include <hip/hip_runtime.h>
#include <cstdint>
#include <cstddef>

constexpr int NN  = 100000;
constexpr int EE  = 1600000;
constexpr int HID = 128;
constexpr int NB  = (NN + 1023) / 1024;   // 98 scan chunks of 1024

typedef float f32x4_t __attribute__((ext_vector_type(4)));
typedef short bf16x8_t __attribute__((ext_vector_type(8)));

static __device__ __forceinline__ short f2bf(float f) {
    union { float f; unsigned u; } x; x.f = f;
    unsigned r = x.u + 0x7FFF + ((x.u >> 16) & 1);   // RN-even
    return (short)(r >> 16);
}
static __device__ __forceinline__ float bf2f(short b) {
    union { unsigned u; float f; } x; x.u = ((unsigned)(unsigned short)b) << 16;
    return x.f;
}

// ---------------------------------------------------------------- degree histogram + arrival rank
// epos[e] = arrival rank of edge e among edges with same dst (makes scatter atomic-free)
__global__ __launch_bounds__(256) void deg_k(const int* __restrict__ src, const int* __restrict__ dst,
                                             int* __restrict__ ocnt, int* __restrict__ icnt,
                                             int* __restrict__ epos) {
    int e0 = (blockIdx.x * 256 + threadIdx.x) * 4;
    if (e0 + 3 < EE) {
        int4 s4 = *(const int4*)(src + e0);
        int4 d4 = *(const int4*)(dst + e0);
        atomicAdd(&ocnt[s4.x], 1);
        atomicAdd(&ocnt[s4.y], 1);
        atomicAdd(&ocnt[s4.z], 1);
        atomicAdd(&ocnt[s4.w], 1);
        int4 p;
        p.x = atomicAdd(&icnt[d4.x], 1);
        p.y = atomicAdd(&icnt[d4.y], 1);
        p.z = atomicAdd(&icnt[d4.z], 1);
        p.w = atomicAdd(&icnt[d4.w], 1);
        *(int4*)(epos + e0) = p;
    } else {
        for (int e = e0; e < EE; e++) {
            atomicAdd(&ocnt[src[e]], 1);
            epos[e] = atomicAdd(&icnt[dst[e]], 1);
        }
    }
}

__global__ __launch_bounds__(256) void norm_k(const int* __restrict__ ocnt, const int* __restrict__ icnt,
                                              float* __restrict__ onorm, float* __restrict__ inorm) {
    int i = blockIdx.x * 256 + threadIdx.x;
    if (i < NN) {
        int oc = ocnt[i]; if (oc < 1) oc = 1;
        int ic = icnt[i]; if (ic < 1) ic = 1;
        onorm[i] = rsqrtf((float)oc);
        inorm[i] = rsqrtf((float)ic);
    }
}

// ---------------------------------------------------------------- CSR rowptr (3-level scan)
__global__ __launch_bounds__(256) void scan_sum_k(const int* __restrict__ icnt, int* __restrict__ bsum) {
    __shared__ int sc[256];
    int b = blockIdx.x, t = threadIdx.x;
    int base = b * 1024 + t * 4;
    int s = 0;
#pragma unroll
    for (int j = 0; j < 4; j++) { int idx = base + j; s += (idx < NN) ? icnt[idx] : 0; }
    sc[t] = s; __syncthreads();
    for (int off = 128; off > 0; off >>= 1) {
        if (t < off) sc[t] += sc[t + off];
        __syncthreads();
    }
    if (t == 0) bsum[b] = sc[0];
}

// one-wave shfl scan over NB (=98) block sums
__global__ void scan_top_k(const int* __restrict__ bsum, int* __restrict__ boff, int* __restrict__ rowptr) {
    int lane = threadIdx.x & 63;
    int v0 = (lane < NB) ? bsum[lane] : 0;
    int v1 = (64 + lane < NB) ? bsum[64 + lane] : 0;
    int s0 = v0;
#pragma unroll
    for (int off = 1; off < 64; off <<= 1) { int t = __shfl_up(s0, off); if (lane >= off) s0 += t; }
    int tot0 = __shfl(s0, 63);
    int s1 = v1;
#pragma unroll
    for (int off = 1; off < 64; off <<= 1) { int t = __shfl_up(s1, off); if (lane >= off) s1 += t; }
    if (lane < NB) boff[lane] = s0 - v0;
    if (64 + lane < NB) boff[64 + lane] = tot0 + s1 - v1;
    if (lane == 63) rowptr[NN] = tot0 + s1;   // == EE
}

__global__ __launch_bounds__(256) void scan_chunk_k(const int* __restrict__ icnt, const int* __restrict__ boff,
                                                    int* __restrict__ rowptr) {
    __shared__ int sc[256];
    int b = blockIdx.x, t = threadIdx.x;
    int base = b * 1024 + t * 4;
    int c[4];
#pragma unroll
    for (int j = 0; j < 4; j++) { int idx = base + j; c[j] = (idx < NN) ? icnt[idx] : 0; }
    int s = c[0] + c[1] + c[2] + c[3];
    sc[t] = s; __syncthreads();
    for (int off = 1; off < 256; off <<= 1) {
        int v = (t >= off) ? sc[t - off] : 0;
        __syncthreads();
        sc[t] += v;
        __syncthreads();
    }
    int excl = sc[t] - s + boff[b];
#pragma unroll
    for (int j = 0; j < 4; j++) {
        int idx = base + j;
        if (idx < NN) rowptr[idx] = excl;
        excl += c[j];
    }
}

// atomic-free scatter using precomputed arrival ranks
__global__ __launch_bounds__(256) void scatter_k(const int* __restrict__ src, const int* __restrict__ dst,
                                                 const int* __restrict__ rowptr, const int* __restrict__ epos,
                                                 int* __restrict__ col) {
    int e0 = (blockIdx.x * 256 + threadIdx.x) * 4;
    if (e0 + 3 < EE) {
        int4 s4 = *(const int4*)(src + e0);
        int4 d4 = *(const int4*)(dst + e0);
        int4 p4 = *(const int4*)(epos + e0);
        col[rowptr[d4.x] + p4.x] = s4.x;
        col[rowptr[d4.y] + p4.y] = s4.y;
        col[rowptr[d4.z] + p4.z] = s4.z;
        col[rowptr[d4.w] + p4.w] = s4.w;
    } else {
        for (int e = e0; e < EE; e++) col[rowptr[dst[e]] + epos[e]] = src[e];
    }
}

// ---------------------------------------------------------------- aggregation
// one wave per dst node; quarter-wave (16 lanes x 2 float4 = 512B) per edge,
// 2 edges in flight per quarter (8 per wave). h is PRE-SCALED by out_norm.
__global__ __launch_bounds__(256) void agg_k(const float4* __restrict__ h4, const int* __restrict__ rowptr,
                                             const int* __restrict__ col, float4* __restrict__ out) {
    int w = (int)((blockIdx.x * 256 + threadIdx.x) >> 6);
    if (w >= NN) return;
    int lane = threadIdx.x & 63;
    int q   = lane >> 4;        // quarter 0..3
    int l16 = lane & 15;
    int beg = rowptr[w], end = rowptr[w + 1];
    float a0x=0.f,a0y=0.f,a0z=0.f,a0w=0.f, a1x=0.f,a1y=0.f,a1z=0.f,a1w=0.f;
    int i = beg + q;
    for (; i + 4 < end; i += 8) {           // per quarter: edges i, i+4
        int s0 = col[i], s1 = col[i + 4];
        float4 u0 = h4[(size_t)s0 * 32 + l16];
        float4 u1 = h4[(size_t)s0 * 32 + l16 + 16];
        float4 v0 = h4[(size_t)s1 * 32 + l16];
        float4 v1 = h4[(size_t)s1 * 32 + l16 + 16];
        a0x += u0.x + v0.x; a0y += u0.y + v0.y; a0z += u0.z + v0.z; a0w += u0.w + v0.w;
        a1x += u1.x + v1.x; a1y += u1.y + v1.y; a1z += u1.z + v1.z; a1w += u1.w + v1.w;
    }
    if (i < end) {
        int s = col[i];
        float4 u0 = h4[(size_t)s * 32 + l16];
        float4 u1 = h4[(size_t)s * 32 + l16 + 16];
        a0x += u0.x; a0y += u0.y; a0z += u0.z; a0w += u0.w;
        a1x += u1.x; a1y += u1.y; a1z += u1.z; a1w += u1.w;
    }
#pragma unroll
    for (int m = 16; m <= 32; m <<= 1) {
        a0x += __shfl_xor(a0x, m); a0y += __shfl_xor(a0y, m);
        a0z += __shfl_xor(a0z, m); a0w += __shfl_xor(a0w, m);
        a1x += __shfl_xor(a1x, m); a1y += __shfl_xor(a1y, m);
        a1z += __shfl_xor(a1z, m); a1w += __shfl_xor(a1w, m);
    }
    if (q == 0) {
        float4 o0; o0.x=a0x; o0.y=a0y; o0.z=a0z; o0.w=a0w;
        float4 o1; o1.x=a1x; o1.y=a1y; o1.z=a1z; o1.w=a1w;
        out[(size_t)w * 32 + l16]      = o0;
        out[(size_t)w * 32 + l16 + 16] = o1;
    }
}

// ---------------------------------------------------------------- split-bf16 MFMA GEMM
// out[r][c] = act( (inscale[r] * in[r][:]) @ W + bias ) * outscale[r]
// A = Ah + Al (bf16 split), W = Wh + Wl staged once per block into LDS in
// B-fragment order; C ~= Ah@Wh + Al@Wh + Ah@Wl via mfma_f32_16x16x32_bf16.
template <int NT, bool RELU, bool INSCALE, bool OUTSCALE>
__global__ __launch_bounds__(256) void mfma_gemm_k(
    const float* __restrict__ in, const float* __restrict__ inscale,
    const float* __restrict__ W, const float* __restrict__ bias,
    float* __restrict__ out, const float* __restrict__ outscale,
    int nrows, int ncols, int ngroups) {

    __shared__ short Bh[NT * 2048];   // [nt][kblk(4)][lane(64)][j(8)]
    __shared__ short Bl[NT * 2048];

    const int t = threadIdx.x;

    if constexpr (NT == 8) {
        for (int j = 0; j < 16; j++) {
            int fi = (j * 256 + t) * 4;
            int k = fi >> 7, n0 = fi & 127;
            float4 wv = *(const float4*)(W + fi);
            float wa[4] = {wv.x, wv.y, wv.z, wv.w};
#pragma unroll
            for (int c = 0; c < 4; c++) {
                int n = n0 + c;
                int nt = n >> 4, kblk = k >> 5, ksub = k & 31;
                int lane_ = ((ksub >> 3) << 4) | (n & 15);
                int sidx = ((nt * 4 + kblk) * 64 + lane_) * 8 + (ksub & 7);
                short hi = f2bf(wa[c]);
                short lo = f2bf(wa[c] - bf2f(hi));
                Bh[sidx] = hi; Bl[sidx] = lo;
            }
        }
    } else {  // classifier: 40 real cols, pad to NT*16=48
        for (int idx = t; idx < 128 * 64; idx += 256) {
            int k = idx >> 6, n = idx & 63;
            if (n < NT * 16) {
                float w = (n < 40) ? W[k * 40 + n] : 0.f;
                int nt = n >> 4, kblk = k >> 5, ksub = k & 31;
                int lane_ = ((ksub >> 3) << 4) | (n & 15);
                int sidx = ((nt * 4 + kblk) * 64 + lane_) * 8 + (ksub & 7);
                short hi = f2bf(w);
                short lo = f2bf(w - bf2f(hi));
                Bh[sidx] = hi; Bl[sidx] = lo;
            }
        }
    }
    __syncthreads();   // LDS read-only below

    const int wave = t >> 6;
    const int lane = t & 63;
    const int m    = lane & 15;
    const int kq   = lane >> 4;

    for (int g = blockIdx.x; g < ngroups; g += gridDim.x) {
        int grow0 = g * 64 + wave * 16;
        int row   = grow0 + m;
        bool rv   = row < nrows;

        bf16x8_t Ah[4], Al[4];
        float s = 1.f;
        if (INSCALE && rv) s = inscale[row];
#pragma unroll
        for (int kb = 0; kb < 4; kb++) {
            const float* ap = in + (size_t)row * 128 + kb * 32 + kq * 8;
            float4 p0, p1;
            if (rv) { p0 = *(const float4*)ap; p1 = *(const float4*)(ap + 4); }
            else    { p0 = make_float4(0,0,0,0); p1 = make_float4(0,0,0,0); }
            float av[8] = {p0.x, p0.y, p0.z, p0.w, p1.x, p1.y, p1.z, p1.w};
#pragma unroll
            for (int j = 0; j < 8; j++) {
                float v = INSCALE ? av[j] * s : av[j];
                short hi = f2bf(v);
                Ah[kb][j] = hi;
                Al[kb][j] = f2bf(v - bf2f(hi));
            }
        }

        int crow0 = grow0 + kq * 4;
        float osr[4];
#pragma unroll
        for (int r = 0; r < 4; r++) {
            int crow = crow0 + r;
            osr[r] = (OUTSCALE && crow < nrows) ? outscale[crow] : 1.f;
        }

#pragma unroll
        for (int nt = 0; nt < NT; nt++) {
            f32x4_t acc = {0.f, 0.f, 0.f, 0.f};
#pragma unroll
            for (int kb = 0; kb < 4; kb++) {
                const bf16x8_t bh = *(const bf16x8_t*)&Bh[((nt * 4 + kb) * 64 + lane) * 8];
                const bf16x8_t bl = *(const bf16x8_t*)&Bl[((nt * 4 + kb) * 64 + lane) * 8];
                acc = __builtin_amdgcn_mfma_f32_16x16x32_bf16(Ah[kb], bh, acc, 0, 0, 0);
                acc = __builtin_amdgcn_mfma_f32_16x16x32_bf16(Al[kb], bh, acc, 0, 0, 0);
                acc = __builtin_amdgcn_mfma_f32_16x16x32_bf16(Ah[kb], bl, acc, 0, 0, 0);
            }
            int ccol = nt * 16 + m;
            bool cv = (NT == 8) ? true : (ccol < ncols);
            float bv = cv ? bias[ccol] : 0.f;
#pragma unroll
            for (int r = 0; r < 4; r++) {
                int crow = crow0 + r;
                if (crow < nrows && cv) {
                    float v = acc[r] + bv;
                    if (RELU) v = fmaxf(v, 0.f);
                    v *= osr[r];
                    out[(size_t)crow * ncols + ccol] = v;
                }
            }
        }
    }
}

// ---------------------------------------------------------------- launch
extern "C" void kernel_launch(void* const* d_in, const int* in_sizes, int n_in,
                              void* d_out, int out_size, void* d_ws, size_t ws_size,
                              hipStream_t stream) {
    const float* x   = (const float*)d_in[0];
    const int*   src = (const int*)d_in[1];
    const int*   dst = (const int*)d_in[2];
    const float* W1  = (const float*)d_in[3];
    const float* b1  = (const float*)d_in[4];
    const float* W2  = (const float*)d_in[5];
    const float* b2  = (const float*)d_in[6];
    const float* Wg  = (const float*)d_in[7];   // [3][128][128]
    const float* bg  = (const float*)d_in[8];   // [3][128]
    const float* Wc  = (const float*)d_in[9];   // [128][40]
    const float* bc  = (const float*)d_in[10];  // [40]
    float* out = (float*)d_out;

    char* ws = (char*)d_ws;
    size_t off = 0;
    auto alloc = [&](size_t bytes) -> void* {
        void* p = ws + off;
        off += (bytes + 255) & ~(size_t)255;
        return p;
    };
    float* h0     = (float*)alloc((size_t)NN * HID * 4);
    float* h1     = (float*)alloc((size_t)NN * HID * 4);
    float* onorm  = (float*)alloc((size_t)NN * 4);
    float* inorm  = (float*)alloc((size_t)NN * 4);
    int*   ocnt   = (int*)alloc((size_t)NN * 4);
    int*   icnt   = (int*)alloc((size_t)NN * 4);
    int*   rowptr = (int*)alloc((size_t)(NN + 1) * 4);
    int*   col    = (int*)alloc((size_t)EE * 4);
    int*   epos   = (int*)alloc((size_t)EE * 4);
    int*   bsum   = (int*)alloc((size_t)NB * 4);
    int*   boff   = (int*)alloc((size_t)NB * 4);

    hipMemsetAsync(ocnt, 0, (size_t)NN * 4, stream);
    hipMemsetAsync(icnt, 0, (size_t)NN * 4, stream);

    const int egrid4 = (EE / 4 + 255) / 256;   // 4 edges/thread
    deg_k<<<egrid4, 256, 0, stream>>>(src, dst, ocnt, icnt, epos);
    norm_k<<<(NN + 255) / 256, 256, 0, stream>>>(ocnt, icnt, onorm, inorm);
    scan_sum_k<<<NB, 256, 0, stream>>>(icnt, bsum);
    scan_top_k<<<1, 64, 0, stream>>>(bsum, boff, rowptr);
    scan_chunk_k<<<NB, 256, 0, stream>>>(icnt, boff, rowptr);
    scatter_k<<<egrid4, 256, 0, stream>>>(src, dst, rowptr, epos, col);

    const int ngroups = (NN + 63) / 64;   // 1563
    const int ggrid   = 512;              // persistent: ~3 groups/block

    mfma_gemm_k<8, false, false, false><<<ggrid, 256, 0, stream>>>(
        x, nullptr, W1, b1, h0, nullptr, NN, 128, ngroups);
    mfma_gemm_k<8, false, false, true><<<ggrid, 256, 0, stream>>>(
        h0, nullptr, W2, b2, h1, onorm, NN, 128, ngroups);
    for (int l = 0; l < 3; l++) {
        agg_k<<<(NN * 64 + 255) / 256, 256, 0, stream>>>(
            (const float4*)h1, rowptr, col, (float4*)h0);
        if (l < 2) {
            mfma_gemm_k<8, true, true, true><<<ggrid, 256, 0, stream>>>(
                h0, inorm, Wg + (size_t)l * 128 * 128, bg + (size_t)l * 128, h1, onorm, NN, 128, ngroups);
        } else {
            mfma_gemm_k<8, true, true, false><<<ggrid, 256, 0, stream>>>(
                h0, inorm, Wg + (size_t)l * 128 * 128, bg + (size_t)l * 128, h1, nullptr, NN, 128, ngroups);
        }
    }
    mfma_gemm_k<3, false, false, false><<<ggrid, 256, 0, stream>>>(
        h1, nullptr, Wc, bc, out, nullptr, NN, 40, ngroups);
}

// Round 4
// 767.314 us; speedup vs baseline: 1.4026x; 1.1305x over previous
//
#include <hip/hip_runtime.h>
#include <cstdint>
#include <cstddef>

constexpr int NN  = 100000;
constexpr int EE  = 1600000;
constexpr int HID = 128;
constexpr int NBUK = (NN + 511) / 512;        // 196 buckets of 512 nodes
constexpr int BLKE = 2048;                    // edges per block in bucket passes
constexpr int NBE  = (EE + BLKE - 1) / BLKE;  // 782 edge blocks
constexpr int MH   = NBUK * NBE;              // 153272 flattened hist entries
constexpr int NSC  = (MH + 1023) / 1024;      // 150 scan chunks

typedef float f32x4_t __attribute__((ext_vector_type(4)));
typedef short bf16x8_t __attribute__((ext_vector_type(8)));

static __device__ __forceinline__ short f2bf(float f) {
    union { float f; unsigned u; } x; x.f = f;
    unsigned r = x.u + 0x7FFF + ((x.u >> 16) & 1);   // RN-even
    return (short)(r >> 16);
}
static __device__ __forceinline__ float bf2f(short b) {
    union { unsigned u; float f; } x; x.u = ((unsigned)(unsigned short)b) << 16;
    return x.f;
}

// ---------------------------------------------------------------- pass 1: per-block bucket histograms (LDS atomics only)
__global__ __launch_bounds__(256) void bh_both_k(const int* __restrict__ src, const int* __restrict__ dst,
                                                 int* __restrict__ bh_d, int* __restrict__ bh_s) {
    __shared__ int hd[NBUK], hs[NBUK];
    int blk = blockIdx.x, t = threadIdx.x;
    for (int i = t; i < NBUK; i += 256) { hd[i] = 0; hs[i] = 0; }
    __syncthreads();
    int e0 = blk * BLKE, e1 = min(e0 + BLKE, EE);
    for (int e = e0 + t; e < e1; e += 256) {
        atomicAdd(&hd[dst[e] >> 9], 1);
        atomicAdd(&hs[src[e] >> 9], 1);
    }
    __syncthreads();
    for (int i = t; i < NBUK; i += 256) {
        bh_d[i * NBE + blk] = hd[i];
        bh_s[i * NBE + blk] = hs[i];
    }
}

// ---------------------------------------------------------------- generic 3-level exclusive scan (length n)
__global__ __launch_bounds__(256) void scan_sum_k(const int* __restrict__ in, int* __restrict__ bsum, int n) {
    __shared__ int sc[256];
    int b = blockIdx.x, t = threadIdx.x;
    int base = b * 1024 + t * 4;
    int s = 0;
#pragma unroll
    for (int j = 0; j < 4; j++) { int idx = base + j; s += (idx < n) ? in[idx] : 0; }
    sc[t] = s; __syncthreads();
    for (int off = 128; off > 0; off >>= 1) {
        if (t < off) sc[t] += sc[t + off];
        __syncthreads();
    }
    if (t == 0) bsum[b] = sc[0];
}

__global__ void scan_top_k(const int* __restrict__ bsum, int* __restrict__ boff, int nb) {
    __shared__ int sc[256];
    int t = threadIdx.x;
    int v = (t < nb) ? bsum[t] : 0;
    sc[t] = v; __syncthreads();
    for (int off = 1; off < 256; off <<= 1) {
        int u = (t >= off) ? sc[t - off] : 0;
        __syncthreads();
        sc[t] += u;
        __syncthreads();
    }
    if (t < nb) boff[t] = sc[t] - v;
}

__global__ __launch_bounds__(256) void scan_chunk_k(const int* __restrict__ in, const int* __restrict__ boff,
                                                    int* __restrict__ out, int n) {
    __shared__ int sc[256];
    int b = blockIdx.x, t = threadIdx.x;
    int base = b * 1024 + t * 4;
    int c[4];
#pragma unroll
    for (int j = 0; j < 4; j++) { int idx = base + j; c[j] = (idx < n) ? in[idx] : 0; }
    int s = c[0] + c[1] + c[2] + c[3];
    sc[t] = s; __syncthreads();
    for (int off = 1; off < 256; off <<= 1) {
        int v = (t >= off) ? sc[t - off] : 0;
        __syncthreads();
        sc[t] += v;
        __syncthreads();
    }
    int excl = sc[t] - s + boff[b];
#pragma unroll
    for (int j = 0; j < 4; j++) {
        int idx = base + j;
        if (idx < n) out[idx] = excl;
        excl += c[j];
    }
}

// ---------------------------------------------------------------- pass 2: scatter into bucket order (LDS cursors)
__global__ __launch_bounds__(256) void scatter_both_k(const int* __restrict__ src, const int* __restrict__ dst,
                                                      const int* __restrict__ off_d, const int* __restrict__ off_s,
                                                      int2* __restrict__ pairs, int* __restrict__ ssorted) {
    __shared__ int cd[NBUK], cs[NBUK];
    int blk = blockIdx.x, t = threadIdx.x;
    for (int i = t; i < NBUK; i += 256) {
        cd[i] = off_d[i * NBE + blk];
        cs[i] = off_s[i * NBE + blk];
    }
    __syncthreads();
    int e0 = blk * BLKE, e1 = min(e0 + BLKE, EE);
    for (int e = e0 + t; e < e1; e += 256) {
        int d = dst[e], s = src[e];
        int pd = atomicAdd(&cd[d >> 9], 1);
        pairs[pd] = make_int2(d, s);
        int ps = atomicAdd(&cs[s >> 9], 1);
        ssorted[ps] = s;
    }
}

// ---------------------------------------------------------------- per-bucket: exact in-deg hist -> inorm, rowptr, col
__global__ __launch_bounds__(256) void bucket_csr_k(const int2* __restrict__ pairs, const int* __restrict__ off_d,
                                                    int* __restrict__ rowptr, int* __restrict__ col,
                                                    float* __restrict__ inorm) {
    __shared__ int hist[512];
    __shared__ int excl[512];
    __shared__ int psum[256];
    int b = blockIdx.x, t = threadIdx.x;
    int base = off_d[b * NBE];
    int endv = (b == NBUK - 1) ? EE : off_d[(b + 1) * NBE];
    hist[t] = 0; hist[t + 256] = 0;
    __syncthreads();
    for (int i = base + t; i < endv; i += 256) atomicAdd(&hist[pairs[i].x & 511], 1);
    __syncthreads();
    // exclusive scan over 512 (pairs of elements per thread)
    int p0 = hist[2 * t], p1 = hist[2 * t + 1];
    int ps = p0 + p1;
    psum[t] = ps; __syncthreads();
    for (int off = 1; off < 256; off <<= 1) {
        int u = (t >= off) ? psum[t - off] : 0;
        __syncthreads();
        psum[t] += u;
        __syncthreads();
    }
    int pex = psum[t] - ps;
    excl[2 * t] = pex; excl[2 * t + 1] = pex + p0;
    __syncthreads();
    int n0 = b * 512;
#pragma unroll
    for (int j = 0; j < 2; j++) {
        int i = 2 * t + j, node = n0 + i;
        if (node < NN) {
            rowptr[node] = base + excl[i];
            int c = hist[i]; if (c < 1) c = 1;
            inorm[node] = rsqrtf((float)c);
        }
    }
    if (b == NBUK - 1 && t == 0) rowptr[NN] = EE;
    __syncthreads();   // all rowptr reads of excl done before cursor mutation
    for (int i = base + t; i < endv; i += 256) {
        int2 p = pairs[i];
        int pos = base + atomicAdd(&excl[p.x & 511], 1);
        col[pos] = p.y;
    }
}

// ---------------------------------------------------------------- per-bucket: exact out-deg hist -> onorm
__global__ __launch_bounds__(256) void bucket_ocnt_k(const int* __restrict__ ssorted, const int* __restrict__ off_s,
                                                     float* __restrict__ onorm) {
    __shared__ int hist[512];
    int b = blockIdx.x, t = threadIdx.x;
    int base = off_s[b * NBE];
    int endv = (b == NBUK - 1) ? EE : off_s[(b + 1) * NBE];
    hist[t] = 0; hist[t + 256] = 0;
    __syncthreads();
    for (int i = base + t; i < endv; i += 256) atomicAdd(&hist[ssorted[i] & 511], 1);
    __syncthreads();
#pragma unroll
    for (int j = 0; j < 2; j++) {
        int i = t + j * 256, node = b * 512 + i;
        if (node < NN) {
            int c = hist[i]; if (c < 1) c = 1;
            onorm[node] = rsqrtf((float)c);
        }
    }
}

// ---------------------------------------------------------------- aggregation
// one wave per dst node; quarter-wave (16 lanes x 2 float4 = 512B) per edge,
// 2 edges in flight per quarter (8 per wave). h is PRE-SCALED by out_norm.
__global__ __launch_bounds__(256) void agg_k(const float4* __restrict__ h4, const int* __restrict__ rowptr,
                                             const int* __restrict__ col, float4* __restrict__ out) {
    int w = (int)((blockIdx.x * 256 + threadIdx.x) >> 6);
    if (w >= NN) return;
    int lane = threadIdx.x & 63;
    int q   = lane >> 4;
    int l16 = lane & 15;
    int beg = rowptr[w], end = rowptr[w + 1];
    float a0x=0.f,a0y=0.f,a0z=0.f,a0w=0.f, a1x=0.f,a1y=0.f,a1z=0.f,a1w=0.f;
    int i = beg + q;
    for (; i + 4 < end; i += 8) {
        int s0 = col[i], s1 = col[i + 4];
        float4 u0 = h4[(size_t)s0 * 32 + l16];
        float4 u1 = h4[(size_t)s0 * 32 + l16 + 16];
        float4 v0 = h4[(size_t)s1 * 32 + l16];
        float4 v1 = h4[(size_t)s1 * 32 + l16 + 16];
        a0x += u0.x + v0.x; a0y += u0.y + v0.y; a0z += u0.z + v0.z; a0w += u0.w + v0.w;
        a1x += u1.x + v1.x; a1y += u1.y + v1.y; a1z += u1.z + v1.z; a1w += u1.w + v1.w;
    }
    if (i < end) {
        int s = col[i];
        float4 u0 = h4[(size_t)s * 32 + l16];
        float4 u1 = h4[(size_t)s * 32 + l16 + 16];
        a0x += u0.x; a0y += u0.y; a0z += u0.z; a0w += u0.w;
        a1x += u1.x; a1y += u1.y; a1z += u1.z; a1w += u1.w;
    }
#pragma unroll
    for (int m = 16; m <= 32; m <<= 1) {
        a0x += __shfl_xor(a0x, m); a0y += __shfl_xor(a0y, m);
        a0z += __shfl_xor(a0z, m); a0w += __shfl_xor(a0w, m);
        a1x += __shfl_xor(a1x, m); a1y += __shfl_xor(a1y, m);
        a1z += __shfl_xor(a1z, m); a1w += __shfl_xor(a1w, m);
    }
    if (q == 0) {
        float4 o0; o0.x=a0x; o0.y=a0y; o0.z=a0z; o0.w=a0w;
        float4 o1; o1.x=a1x; o1.y=a1y; o1.z=a1z; o1.w=a1w;
        out[(size_t)w * 32 + l16]      = o0;
        out[(size_t)w * 32 + l16 + 16] = o1;
    }
}

// ---------------------------------------------------------------- split-bf16 MFMA GEMM
// out[r][c] = act( (inscale[r] * in[r][:]) @ W + bias ) * outscale[r]
template <int NT, bool RELU, bool INSCALE, bool OUTSCALE>
__global__ __launch_bounds__(256) void mfma_gemm_k(
    const float* __restrict__ in, const float* __restrict__ inscale,
    const float* __restrict__ W, const float* __restrict__ bias,
    float* __restrict__ out, const float* __restrict__ outscale,
    int nrows, int ncols, int ngroups) {

    __shared__ short Bh[NT * 2048];   // [nt][kblk(4)][lane(64)][j(8)]
    __shared__ short Bl[NT * 2048];

    const int t = threadIdx.x;

    if constexpr (NT == 8) {
        for (int j = 0; j < 16; j++) {
            int fi = (j * 256 + t) * 4;
            int k = fi >> 7, n0 = fi & 127;
            float4 wv = *(const float4*)(W + fi);
            float wa[4] = {wv.x, wv.y, wv.z, wv.w};
#pragma unroll
            for (int c = 0; c < 4; c++) {
                int n = n0 + c;
                int nt = n >> 4, kblk = k >> 5, ksub = k & 31;
                int lane_ = ((ksub >> 3) << 4) | (n & 15);
                int sidx = ((nt * 4 + kblk) * 64 + lane_) * 8 + (ksub & 7);
                short hi = f2bf(wa[c]);
                short lo = f2bf(wa[c] - bf2f(hi));
                Bh[sidx] = hi; Bl[sidx] = lo;
            }
        }
    } else {  // classifier: 40 real cols, pad to NT*16=48
        for (int idx = t; idx < 128 * 64; idx += 256) {
            int k = idx >> 6, n = idx & 63;
            if (n < NT * 16) {
                float w = (n < 40) ? W[k * 40 + n] : 0.f;
                int nt = n >> 4, kblk = k >> 5, ksub = k & 31;
                int lane_ = ((ksub >> 3) << 4) | (n & 15);
                int sidx = ((nt * 4 + kblk) * 64 + lane_) * 8 + (ksub & 7);
                short hi = f2bf(w);
                short lo = f2bf(w - bf2f(hi));
                Bh[sidx] = hi; Bl[sidx] = lo;
            }
        }
    }
    __syncthreads();   // LDS read-only below

    const int wave = t >> 6;
    const int lane = t & 63;
    const int m    = lane & 15;
    const int kq   = lane >> 4;

    for (int g = blockIdx.x; g < ngroups; g += gridDim.x) {
        int grow0 = g * 64 + wave * 16;
        int row   = grow0 + m;
        bool rv   = row < nrows;

        bf16x8_t Ah[4], Al[4];
        float s = 1.f;
        if (INSCALE && rv) s = inscale[row];
#pragma unroll
        for (int kb = 0; kb < 4; kb++) {
            const float* ap = in + (size_t)row * 128 + kb * 32 + kq * 8;
            float4 p0, p1;
            if (rv) { p0 = *(const float4*)ap; p1 = *(const float4*)(ap + 4); }
            else    { p0 = make_float4(0,0,0,0); p1 = make_float4(0,0,0,0); }
            float av[8] = {p0.x, p0.y, p0.z, p0.w, p1.x, p1.y, p1.z, p1.w};
#pragma unroll
            for (int j = 0; j < 8; j++) {
                float v = INSCALE ? av[j] * s : av[j];
                short hi = f2bf(v);
                Ah[kb][j] = hi;
                Al[kb][j] = f2bf(v - bf2f(hi));
            }
        }

        int crow0 = grow0 + kq * 4;
        float osr[4];
#pragma unroll
        for (int r = 0; r < 4; r++) {
            int crow = crow0 + r;
            osr[r] = (OUTSCALE && crow < nrows) ? outscale[crow] : 1.f;
        }

#pragma unroll
        for (int nt = 0; nt < NT; nt++) {
            f32x4_t acc = {0.f, 0.f, 0.f, 0.f};
#pragma unroll
            for (int kb = 0; kb < 4; kb++) {
                const bf16x8_t bh = *(const bf16x8_t*)&Bh[((nt * 4 + kb) * 64 + lane) * 8];
                const bf16x8_t bl = *(const bf16x8_t*)&Bl[((nt * 4 + kb) * 64 + lane) * 8];
                acc = __builtin_amdgcn_mfma_f32_16x16x32_bf16(Ah[kb], bh, acc, 0, 0, 0);
                acc = __builtin_amdgcn_mfma_f32_16x16x32_bf16(Al[kb], bh, acc, 0, 0, 0);
                acc = __builtin_amdgcn_mfma_f32_16x16x32_bf16(Ah[kb], bl, acc, 0, 0, 0);
            }
            int ccol = nt * 16 + m;
            bool cv = (NT == 8) ? true : (ccol < ncols);
            float bv = cv ? bias[ccol] : 0.f;
#pragma unroll
            for (int r = 0; r < 4; r++) {
                int crow = crow0 + r;
                if (crow < nrows && cv) {
                    float v = acc[r] + bv;
                    if (RELU) v = fmaxf(v, 0.f);
                    v *= osr[r];
                    out[(size_t)crow * ncols + ccol] = v;
                }
            }
        }
    }
}

// ---------------------------------------------------------------- launch
extern "C" void kernel_launch(void* const* d_in, const int* in_sizes, int n_in,
                              void* d_out, int out_size, void* d_ws, size_t ws_size,
                              hipStream_t stream) {
    const float* x   = (const float*)d_in[0];
    const int*   src = (const int*)d_in[1];
    const int*   dst = (const int*)d_in[2];
    const float* W1  = (const float*)d_in[3];
    const float* b1  = (const float*)d_in[4];
    const float* W2  = (const float*)d_in[5];
    const float* b2  = (const float*)d_in[6];
    const float* Wg  = (const float*)d_in[7];   // [3][128][128]
    const float* bg  = (const float*)d_in[8];   // [3][128]
    const float* Wc  = (const float*)d_in[9];   // [128][40]
    const float* bc  = (const float*)d_in[10];  // [40]
    float* out = (float*)d_out;

    char* ws = (char*)d_ws;
    size_t off = 0;
    auto alloc = [&](size_t bytes) -> void* {
        void* p = ws + off;
        off += (bytes + 255) & ~(size_t)255;
        return p;
    };
    float* h0     = (float*)alloc((size_t)NN * HID * 4);
    float* h1     = (float*)alloc((size_t)NN * HID * 4);
    float* onorm  = (float*)alloc((size_t)NN * 4);
    float* inorm  = (float*)alloc((size_t)NN * 4);
    int*   rowptr = (int*)alloc((size_t)(NN + 1) * 4);
    int*   col    = (int*)alloc((size_t)EE * 4);
    int*   bh_d   = (int*)alloc((size_t)MH * 4);
    int*   bh_s   = (int*)alloc((size_t)MH * 4);
    int*   off_d  = (int*)alloc((size_t)MH * 4);
    int*   off_s  = (int*)alloc((size_t)MH * 4);
    int*   bsum   = (int*)alloc((size_t)NSC * 4);
    int*   boff   = (int*)alloc((size_t)NSC * 4);
    // sort payload buffers alias h0 (consumed before GEMM1 writes h0)
    int2*  pairs   = (int2*)h0;                     // 12.8 MB
    int*   ssorted = (int*)(h0 + (size_t)EE * 2);   // 6.4 MB, after pairs

    // ---- CSR build (no global atomics)
    bh_both_k<<<NBE, 256, 0, stream>>>(src, dst, bh_d, bh_s);
    scan_sum_k<<<NSC, 256, 0, stream>>>(bh_d, bsum, MH);
    scan_top_k<<<1, 256, 0, stream>>>(bsum, boff, NSC);
    scan_chunk_k<<<NSC, 256, 0, stream>>>(bh_d, boff, off_d, MH);
    scan_sum_k<<<NSC, 256, 0, stream>>>(bh_s, bsum, MH);
    scan_top_k<<<1, 256, 0, stream>>>(bsum, boff, NSC);
    scan_chunk_k<<<NSC, 256, 0, stream>>>(bh_s, boff, off_s, MH);
    scatter_both_k<<<NBE, 256, 0, stream>>>(src, dst, off_d, off_s, pairs, ssorted);
    bucket_csr_k<<<NBUK, 256, 0, stream>>>(pairs, off_d, rowptr, col, inorm);
    bucket_ocnt_k<<<NBUK, 256, 0, stream>>>(ssorted, off_s, onorm);

    const int ngroups = (NN + 63) / 64;   // 1563
    const int ggrid   = 512;              // persistent: ~3 groups/block

    mfma_gemm_k<8, false, false, false><<<ggrid, 256, 0, stream>>>(
        x, nullptr, W1, b1, h0, nullptr, NN, 128, ngroups);
    mfma_gemm_k<8, false, false, true><<<ggrid, 256, 0, stream>>>(
        h0, nullptr, W2, b2, h1, onorm, NN, 128, ngroups);
    for (int l = 0; l < 3; l++) {
        agg_k<<<(NN * 64 + 255) / 256, 256, 0, stream>>>(
            (const float4*)h1, rowptr, col, (float4*)h0);
        if (l < 2) {
            mfma_gemm_k<8, true, true, true><<<ggrid, 256, 0, stream>>>(
                h0, inorm, Wg + (size_t)l * 128 * 128, bg + (size_t)l * 128, h1, onorm, NN, 128, ngroups);
        } else {
            mfma_gemm_k<8, true, true, false><<<ggrid, 256, 0, stream>>>(
                h0, inorm, Wg + (size_t)l * 128 * 128, bg + (size_t)l * 128, h1, nullptr, NN, 128, ngroups);
        }
    }
    mfma_gemm_k<3, false, false, false><<<ggrid, 256, 0, stream>>>(
        h1, nullptr, Wc, bc, out, nullptr, NN, 40, ngroups);
}

// Round 5
// 613.617 us; speedup vs baseline: 1.7540x; 1.2505x over previous
//
#include <hip/hip_runtime.h>
#include <hip/hip_fp16.h>
#include <cstdint>
#include <cstddef>

constexpr int NN  = 100000;
constexpr int EE  = 1600000;
constexpr int HID = 128;
constexpr int NBUK = (NN + 511) / 512;        // 196 buckets of 512 nodes
constexpr int BLKE = 2048;                    // edges per block in bucket passes
constexpr int NBE  = (EE + BLKE - 1) / BLKE;  // 782 edge blocks
constexpr int MH   = NBUK * NBE;              // 153272 flattened hist entries
constexpr int NSC  = (MH + 1023) / 1024;      // 150 scan chunks

typedef float f32x4_t __attribute__((ext_vector_type(4)));
typedef short bf16x8_t __attribute__((ext_vector_type(8)));

static __device__ __forceinline__ short f2bf(float f) {
    union { float f; unsigned u; } x; x.f = f;
    unsigned r = x.u + 0x7FFF + ((x.u >> 16) & 1);   // RN-even
    return (short)(r >> 16);
}
static __device__ __forceinline__ float bf2f(short b) {
    union { unsigned u; float f; } x; x.u = ((unsigned)(unsigned short)b) << 16;
    return x.f;
}

// ---------------------------------------------------------------- pass 1: per-block bucket histograms (LDS atomics only)
__global__ __launch_bounds__(256) void bh_both_k(const int* __restrict__ src, const int* __restrict__ dst,
                                                 int* __restrict__ bh_d, int* __restrict__ bh_s) {
    __shared__ int hd[NBUK], hs[NBUK];
    int blk = blockIdx.x, t = threadIdx.x;
    for (int i = t; i < NBUK; i += 256) { hd[i] = 0; hs[i] = 0; }
    __syncthreads();
    int e0 = blk * BLKE, e1 = min(e0 + BLKE, EE);
    for (int e = e0 + t; e < e1; e += 256) {
        atomicAdd(&hd[dst[e] >> 9], 1);
        atomicAdd(&hs[src[e] >> 9], 1);
    }
    __syncthreads();
    for (int i = t; i < NBUK; i += 256) {
        bh_d[i * NBE + blk] = hd[i];
        bh_s[i * NBE + blk] = hs[i];
    }
}

// ---------------------------------------------------------------- generic 3-level exclusive scan (length n)
__global__ __launch_bounds__(256) void scan_sum_k(const int* __restrict__ in, int* __restrict__ bsum, int n) {
    __shared__ int sc[256];
    int b = blockIdx.x, t = threadIdx.x;
    int base = b * 1024 + t * 4;
    int s = 0;
#pragma unroll
    for (int j = 0; j < 4; j++) { int idx = base + j; s += (idx < n) ? in[idx] : 0; }
    sc[t] = s; __syncthreads();
    for (int off = 128; off > 0; off >>= 1) {
        if (t < off) sc[t] += sc[t + off];
        __syncthreads();
    }
    if (t == 0) bsum[b] = sc[0];
}

__global__ void scan_top_k(const int* __restrict__ bsum, int* __restrict__ boff, int nb) {
    __shared__ int sc[256];
    int t = threadIdx.x;
    int v = (t < nb) ? bsum[t] : 0;
    sc[t] = v; __syncthreads();
    for (int off = 1; off < 256; off <<= 1) {
        int u = (t >= off) ? sc[t - off] : 0;
        __syncthreads();
        sc[t] += u;
        __syncthreads();
    }
    if (t < nb) boff[t] = sc[t] - v;
}

__global__ __launch_bounds__(256) void scan_chunk_k(const int* __restrict__ in, const int* __restrict__ boff,
                                                    int* __restrict__ out, int n) {
    __shared__ int sc[256];
    int b = blockIdx.x, t = threadIdx.x;
    int base = b * 1024 + t * 4;
    int c[4];
#pragma unroll
    for (int j = 0; j < 4; j++) { int idx = base + j; c[j] = (idx < n) ? in[idx] : 0; }
    int s = c[0] + c[1] + c[2] + c[3];
    sc[t] = s; __syncthreads();
    for (int off = 1; off < 256; off <<= 1) {
        int v = (t >= off) ? sc[t - off] : 0;
        __syncthreads();
        sc[t] += v;
        __syncthreads();
    }
    int excl = sc[t] - s + boff[b];
#pragma unroll
    for (int j = 0; j < 4; j++) {
        int idx = base + j;
        if (idx < n) out[idx] = excl;
        excl += c[j];
    }
}

// ---------------------------------------------------------------- pass 2: scatter into bucket order (LDS cursors)
__global__ __launch_bounds__(256) void scatter_both_k(const int* __restrict__ src, const int* __restrict__ dst,
                                                      const int* __restrict__ off_d, const int* __restrict__ off_s,
                                                      int2* __restrict__ pairs, int* __restrict__ ssorted) {
    __shared__ int cd[NBUK], cs[NBUK];
    int blk = blockIdx.x, t = threadIdx.x;
    for (int i = t; i < NBUK; i += 256) {
        cd[i] = off_d[i * NBE + blk];
        cs[i] = off_s[i * NBE + blk];
    }
    __syncthreads();
    int e0 = blk * BLKE, e1 = min(e0 + BLKE, EE);
    for (int e = e0 + t; e < e1; e += 256) {
        int d = dst[e], s = src[e];
        int pd = atomicAdd(&cd[d >> 9], 1);
        pairs[pd] = make_int2(d, s);
        int ps = atomicAdd(&cs[s >> 9], 1);
        ssorted[ps] = s;
    }
}

// ---------------------------------------------------------------- per-bucket: exact in-deg hist -> inorm, rowptr, col
__global__ __launch_bounds__(256) void bucket_csr_k(const int2* __restrict__ pairs, const int* __restrict__ off_d,
                                                    int* __restrict__ rowptr, int* __restrict__ col,
                                                    float* __restrict__ inorm) {
    __shared__ int hist[512];
    __shared__ int excl[512];
    __shared__ int psum[256];
    int b = blockIdx.x, t = threadIdx.x;
    int base = off_d[b * NBE];
    int endv = (b == NBUK - 1) ? EE : off_d[(b + 1) * NBE];
    hist[t] = 0; hist[t + 256] = 0;
    __syncthreads();
    for (int i = base + t; i < endv; i += 256) atomicAdd(&hist[pairs[i].x & 511], 1);
    __syncthreads();
    int p0 = hist[2 * t], p1 = hist[2 * t + 1];
    int ps = p0 + p1;
    psum[t] = ps; __syncthreads();
    for (int off = 1; off < 256; off <<= 1) {
        int u = (t >= off) ? psum[t - off] : 0;
        __syncthreads();
        psum[t] += u;
        __syncthreads();
    }
    int pex = psum[t] - ps;
    excl[2 * t] = pex; excl[2 * t + 1] = pex + p0;
    __syncthreads();
    int n0 = b * 512;
#pragma unroll
    for (int j = 0; j < 2; j++) {
        int i = 2 * t + j, node = n0 + i;
        if (node < NN) {
            rowptr[node] = base + excl[i];
            int c = hist[i]; if (c < 1) c = 1;
            inorm[node] = rsqrtf((float)c);
        }
    }
    if (b == NBUK - 1 && t == 0) rowptr[NN] = EE;
    __syncthreads();
    for (int i = base + t; i < endv; i += 256) {
        int2 p = pairs[i];
        int pos = base + atomicAdd(&excl[p.x & 511], 1);
        col[pos] = p.y;
    }
}

// ---------------------------------------------------------------- per-bucket: exact out-deg hist -> onorm
__global__ __launch_bounds__(256) void bucket_ocnt_k(const int* __restrict__ ssorted, const int* __restrict__ off_s,
                                                     float* __restrict__ onorm) {
    __shared__ int hist[512];
    int b = blockIdx.x, t = threadIdx.x;
    int base = off_s[b * NBE];
    int endv = (b == NBUK - 1) ? EE : off_s[(b + 1) * NBE];
    hist[t] = 0; hist[t + 256] = 0;
    __syncthreads();
    for (int i = base + t; i < endv; i += 256) atomicAdd(&hist[ssorted[i] & 511], 1);
    __syncthreads();
#pragma unroll
    for (int j = 0; j < 2; j++) {
        int i = t + j * 256, node = b * 512 + i;
        if (node < NN) {
            int c = hist[i]; if (c < 1) c = 1;
            onorm[node] = rsqrtf((float)c);
        }
    }
}

// ---------------------------------------------------------------- aggregation (fp16 gather, fp32 accumulate)
// one wave per dst node; quarter-wave (16 lanes x 16B = one 256B fp16 row),
// 4 edges in flight per quarter (16 per wave). h16 is PRE-SCALED by out_norm.
__global__ __launch_bounds__(256) void agg_k(const float4* __restrict__ h16, const int* __restrict__ rowptr,
                                             const int* __restrict__ col, float4* __restrict__ out) {
    int w = (int)((blockIdx.x * 256 + threadIdx.x) >> 6);
    if (w >= NN) return;
    int lane = threadIdx.x & 63;
    int q   = lane >> 4;
    int l16 = lane & 15;
    int beg = rowptr[w], end = rowptr[w + 1];
    float acc[8];
#pragma unroll
    for (int j = 0; j < 8; j++) acc[j] = 0.f;

    union HU { float4 f4; __half2 h2[4]; };
    int i = beg + q;
    for (; i + 12 < end; i += 16) {        // per quarter: edges i, i+4, i+8, i+12
        int s0 = col[i], s1 = col[i + 4], s2 = col[i + 8], s3 = col[i + 12];
        HU u0, u1, u2, u3;
        u0.f4 = h16[(size_t)s0 * 16 + l16];
        u1.f4 = h16[(size_t)s1 * 16 + l16];
        u2.f4 = h16[(size_t)s2 * 16 + l16];
        u3.f4 = h16[(size_t)s3 * 16 + l16];
#pragma unroll
        for (int p = 0; p < 4; p++) {
            float2 a = __half22float2(u0.h2[p]);
            float2 b = __half22float2(u1.h2[p]);
            float2 c = __half22float2(u2.h2[p]);
            float2 d = __half22float2(u3.h2[p]);
            acc[2 * p]     += (a.x + b.x) + (c.x + d.x);
            acc[2 * p + 1] += (a.y + b.y) + (c.y + d.y);
        }
    }
    for (; i < end; i += 4) {
        int s = col[i];
        HU u; u.f4 = h16[(size_t)s * 16 + l16];
#pragma unroll
        for (int p = 0; p < 4; p++) {
            float2 a = __half22float2(u.h2[p]);
            acc[2 * p]     += a.x;
            acc[2 * p + 1] += a.y;
        }
    }
#pragma unroll
    for (int m = 16; m <= 32; m <<= 1)
#pragma unroll
        for (int j = 0; j < 8; j++) acc[j] += __shfl_xor(acc[j], m);
    if (q == 0) {
        float4 o0, o1;
        o0.x = acc[0]; o0.y = acc[1]; o0.z = acc[2]; o0.w = acc[3];
        o1.x = acc[4]; o1.y = acc[5]; o1.z = acc[6]; o1.w = acc[7];
        // fp32 row = 512B = 16 lanes x 2 float4 (interleaved halves)
        out[(size_t)w * 32 + l16 * 2]     = o0;
        out[(size_t)w * 32 + l16 * 2 + 1] = o1;
    }
}

// ---------------------------------------------------------------- split-bf16 MFMA GEMM
// out[r][c] = act( (inscale[r] * in[r][:]) @ W + bias ) * outscale[r]
// OUTHALF: store output as fp16 (consumed only by agg_k)
template <int NT, bool RELU, bool INSCALE, bool OUTSCALE, bool OUTHALF>
__global__ __launch_bounds__(256) void mfma_gemm_k(
    const float* __restrict__ in, const float* __restrict__ inscale,
    const float* __restrict__ W, const float* __restrict__ bias,
    void* __restrict__ outp, const float* __restrict__ outscale,
    int nrows, int ncols, int ngroups) {

    __shared__ short Bh[NT * 2048];   // [nt][kblk(4)][lane(64)][j(8)]
    __shared__ short Bl[NT * 2048];

    const int t = threadIdx.x;

    if constexpr (NT == 8) {
        for (int j = 0; j < 16; j++) {
            int fi = (j * 256 + t) * 4;
            int k = fi >> 7, n0 = fi & 127;
            float4 wv = *(const float4*)(W + fi);
            float wa[4] = {wv.x, wv.y, wv.z, wv.w};
#pragma unroll
            for (int c = 0; c < 4; c++) {
                int n = n0 + c;
                int nt = n >> 4, kblk = k >> 5, ksub = k & 31;
                int lane_ = ((ksub >> 3) << 4) | (n & 15);
                int sidx = ((nt * 4 + kblk) * 64 + lane_) * 8 + (ksub & 7);
                short hi = f2bf(wa[c]);
                short lo = f2bf(wa[c] - bf2f(hi));
                Bh[sidx] = hi; Bl[sidx] = lo;
            }
        }
    } else {  // classifier: 40 real cols, pad to NT*16=48
        for (int idx = t; idx < 128 * 64; idx += 256) {
            int k = idx >> 6, n = idx & 63;
            if (n < NT * 16) {
                float w = (n < 40) ? W[k * 40 + n] : 0.f;
                int nt = n >> 4, kblk = k >> 5, ksub = k & 31;
                int lane_ = ((ksub >> 3) << 4) | (n & 15);
                int sidx = ((nt * 4 + kblk) * 64 + lane_) * 8 + (ksub & 7);
                short hi = f2bf(w);
                short lo = f2bf(w - bf2f(hi));
                Bh[sidx] = hi; Bl[sidx] = lo;
            }
        }
    }
    __syncthreads();   // LDS read-only below

    const int wave = t >> 6;
    const int lane = t & 63;
    const int m    = lane & 15;
    const int kq   = lane >> 4;

    for (int g = blockIdx.x; g < ngroups; g += gridDim.x) {
        int grow0 = g * 64 + wave * 16;
        int row   = grow0 + m;
        bool rv   = row < nrows;

        bf16x8_t Ah[4], Al[4];
        float s = 1.f;
        if (INSCALE && rv) s = inscale[row];
#pragma unroll
        for (int kb = 0; kb < 4; kb++) {
            const float* ap = in + (size_t)row * 128 + kb * 32 + kq * 8;
            float4 p0, p1;
            if (rv) { p0 = *(const float4*)ap; p1 = *(const float4*)(ap + 4); }
            else    { p0 = make_float4(0,0,0,0); p1 = make_float4(0,0,0,0); }
            float av[8] = {p0.x, p0.y, p0.z, p0.w, p1.x, p1.y, p1.z, p1.w};
#pragma unroll
            for (int j = 0; j < 8; j++) {
                float v = INSCALE ? av[j] * s : av[j];
                short hi = f2bf(v);
                Ah[kb][j] = hi;
                Al[kb][j] = f2bf(v - bf2f(hi));
            }
        }

        int crow0 = grow0 + kq * 4;
        float osr[4];
#pragma unroll
        for (int r = 0; r < 4; r++) {
            int crow = crow0 + r;
            osr[r] = (OUTSCALE && crow < nrows) ? outscale[crow] : 1.f;
        }

#pragma unroll
        for (int nt = 0; nt < NT; nt++) {
            f32x4_t acc = {0.f, 0.f, 0.f, 0.f};
#pragma unroll
            for (int kb = 0; kb < 4; kb++) {
                const bf16x8_t bh = *(const bf16x8_t*)&Bh[((nt * 4 + kb) * 64 + lane) * 8];
                const bf16x8_t bl = *(const bf16x8_t*)&Bl[((nt * 4 + kb) * 64 + lane) * 8];
                acc = __builtin_amdgcn_mfma_f32_16x16x32_bf16(Ah[kb], bh, acc, 0, 0, 0);
                acc = __builtin_amdgcn_mfma_f32_16x16x32_bf16(Al[kb], bh, acc, 0, 0, 0);
                acc = __builtin_amdgcn_mfma_f32_16x16x32_bf16(Ah[kb], bl, acc, 0, 0, 0);
            }
            int ccol = nt * 16 + m;
            bool cv = (NT == 8) ? true : (ccol < ncols);
            float bv = cv ? bias[ccol] : 0.f;
#pragma unroll
            for (int r = 0; r < 4; r++) {
                int crow = crow0 + r;
                if (crow < nrows && cv) {
                    float v = acc[r] + bv;
                    if (RELU) v = fmaxf(v, 0.f);
                    v *= osr[r];
                    if (OUTHALF) ((__half*)outp)[(size_t)crow * ncols + ccol] = __float2half_rn(v);
                    else         ((float*)outp)[(size_t)crow * ncols + ccol] = v;
                }
            }
        }
    }
}

// ---------------------------------------------------------------- launch
extern "C" void kernel_launch(void* const* d_in, const int* in_sizes, int n_in,
                              void* d_out, int out_size, void* d_ws, size_t ws_size,
                              hipStream_t stream) {
    const float* x   = (const float*)d_in[0];
    const int*   src = (const int*)d_in[1];
    const int*   dst = (const int*)d_in[2];
    const float* W1  = (const float*)d_in[3];
    const float* b1  = (const float*)d_in[4];
    const float* W2  = (const float*)d_in[5];
    const float* b2  = (const float*)d_in[6];
    const float* Wg  = (const float*)d_in[7];   // [3][128][128]
    const float* bg  = (const float*)d_in[8];   // [3][128]
    const float* Wc  = (const float*)d_in[9];   // [128][40]
    const float* bc  = (const float*)d_in[10];  // [40]
    float* out = (float*)d_out;

    char* ws = (char*)d_ws;
    size_t off = 0;
    auto alloc = [&](size_t bytes) -> void* {
        void* p = ws + off;
        off += (bytes + 255) & ~(size_t)255;
        return p;
    };
    float*  h0     = (float*)alloc((size_t)NN * HID * 4);
    float*  h1     = (float*)alloc((size_t)NN * HID * 4);
    __half* h16    = (__half*)alloc((size_t)NN * HID * 2);
    float*  onorm  = (float*)alloc((size_t)NN * 4);
    float*  inorm  = (float*)alloc((size_t)NN * 4);
    int*    rowptr = (int*)alloc((size_t)(NN + 1) * 4);
    int*    col    = (int*)alloc((size_t)EE * 4);
    int*    bh_d   = (int*)alloc((size_t)MH * 4);
    int*    bh_s   = (int*)alloc((size_t)MH * 4);
    int*    off_d  = (int*)alloc((size_t)MH * 4);
    int*    off_s  = (int*)alloc((size_t)MH * 4);
    int*    bsum   = (int*)alloc((size_t)NSC * 4);
    int*    boff   = (int*)alloc((size_t)NSC * 4);
    // sort payload buffers alias h0 (consumed before GEMM1 writes h0)
    int2*  pairs   = (int2*)h0;                     // 12.8 MB
    int*   ssorted = (int*)(h0 + (size_t)EE * 2);   // 6.4 MB, after pairs

    // ---- CSR build (no global atomics)
    bh_both_k<<<NBE, 256, 0, stream>>>(src, dst, bh_d, bh_s);
    scan_sum_k<<<NSC, 256, 0, stream>>>(bh_d, bsum, MH);
    scan_top_k<<<1, 256, 0, stream>>>(bsum, boff, NSC);
    scan_chunk_k<<<NSC, 256, 0, stream>>>(bh_d, boff, off_d, MH);
    scan_sum_k<<<NSC, 256, 0, stream>>>(bh_s, bsum, MH);
    scan_top_k<<<1, 256, 0, stream>>>(bsum, boff, NSC);
    scan_chunk_k<<<NSC, 256, 0, stream>>>(bh_s, boff, off_s, MH);
    scatter_both_k<<<NBE, 256, 0, stream>>>(src, dst, off_d, off_s, pairs, ssorted);
    bucket_csr_k<<<NBUK, 256, 0, stream>>>(pairs, off_d, rowptr, col, inorm);
    bucket_ocnt_k<<<NBUK, 256, 0, stream>>>(ssorted, off_s, onorm);

    const int ngroups = (NN + 63) / 64;   // 1563
    const int ggrid   = 512;              // persistent: ~3 groups/block

    // h0 = x @ W1 + b1                               (fp32 out, feeds GEMM2)
    mfma_gemm_k<8, false, false, false, false><<<ggrid, 256, 0, stream>>>(
        x, nullptr, W1, b1, h0, nullptr, NN, 128, ngroups);
    // h16 = (h0 @ W2 + b2) * onorm                   (fp16 out, feeds agg)
    mfma_gemm_k<8, false, false, true, true><<<ggrid, 256, 0, stream>>>(
        h0, nullptr, W2, b2, h16, onorm, NN, 128, ngroups);
    for (int l = 0; l < 3; l++) {
        agg_k<<<(NN * 64 + 255) / 256, 256, 0, stream>>>(
            (const float4*)h16, rowptr, col, (float4*)h0);
        if (l < 2) {
            // h16 = relu(inorm*h0 @ Wg + bg) * onorm (fp16 out, feeds agg)
            mfma_gemm_k<8, true, true, true, true><<<ggrid, 256, 0, stream>>>(
                h0, inorm, Wg + (size_t)l * 128 * 128, bg + (size_t)l * 128, h16, onorm, NN, 128, ngroups);
        } else {
            // h1 = relu(inorm*h0 @ Wg + bg)          (fp32 out, feeds classifier)
            mfma_gemm_k<8, true, true, false, false><<<ggrid, 256, 0, stream>>>(
                h0, inorm, Wg + (size_t)l * 128 * 128, bg + (size_t)l * 128, h1, nullptr, NN, 128, ngroups);
        }
    }
    // out = h1 @ Wc + bc
    mfma_gemm_k<3, false, false, false, false><<<ggrid, 256, 0, stream>>>(
        h1, nullptr, Wc, bc, out, nullptr, NN, 40, ngroups);
}